// Round 11
// baseline (428.721 us; speedup 1.0000x reference)
//
#include <hip/hip_runtime.h>
#include <hip/hip_fp16.h>
#include <math.h>
#include <limits.h>

#define FIN 128
#define NEG_SLOPE 0.2f

typedef _Float16 f16x8 __attribute__((ext_vector_type(8)));
typedef float f32x4 __attribute__((ext_vector_type(4)));
typedef float f32x2 __attribute__((ext_vector_type(2)));

// ---- VOP3P packed fp32 (CDNA dual-FP32). hipcc never auto-forms these. ----
static __device__ __forceinline__ f32x2 pk_add(f32x2 a, f32x2 b) {
    f32x2 d; asm("v_pk_add_f32 %0, %1, %2" : "=v"(d) : "v"(a), "v"(b)); return d;
}
static __device__ __forceinline__ f32x2 pk_fma(f32x2 a, f32x2 b, f32x2 c) {
    f32x2 d; asm("v_pk_fma_f32 %0, %1, %2, %3" : "=v"(d) : "v"(a), "v"(b), "v"(c)); return d;
}

static __device__ __forceinline__ f32x2 h2f2x(unsigned int u) {
    __half2 h = *reinterpret_cast<__half2*>(&u);
    float2 f = __half22float2(h);
    return (f32x2){f.x, f.y};
}

// DPP tree-add within 8-lane groups (xor1, xor2, xor4). Full-rate VALU, no LDS.
template <int CTRL>
static __device__ __forceinline__ float dpp_add(float x) {
    int t = __builtin_amdgcn_update_dpp(0, __builtin_bit_cast(int, x), CTRL, 0xF, 0xF, true);
    return x + __builtin_bit_cast(float, t);
}
static __device__ __forceinline__ float reduce8_dpp(float p) {
    p = dpp_add<0xB1>(p);    // quad_perm [1,0,3,2]  : xor 1
    p = dpp_add<0x4E>(p);    // quad_perm [2,3,0,1]  : xor 2
    p = dpp_add<0x141>(p);   // row_half_mirror      : xor 4
    return p;
}

// ---------------- CSR build (XCD-range-partitioned hist/scatter) ----------------
// range = blockIdx & 7 (default XCD round-robin): all atomics/writes for one
// node-range stay in one XCD's L2 -> dense writeback instead of 64B-line spray.

__global__ void k_hist_part(const int* __restrict__ dst, int* __restrict__ counts,
                            int E, int span) {
    const int r = blockIdx.x & 7;
    const int chunk = blockIdx.x >> 3;
    const int nchunks = gridDim.x >> 3;
    const int lo = r * span, hi = lo + span;
    const int per = (E + nchunks - 1) / nchunks;
    const int e1 = min(E, (chunk + 1) * per);
    for (int e = chunk * per + threadIdx.x; e < e1; e += blockDim.x) {
        int d = dst[e];
        if (d >= lo && d < hi) atomicAdd(&counts[d], 1);
    }
}

__global__ void k_scatter_part(const int* __restrict__ dst, const int* __restrict__ rowptr,
                               int* __restrict__ nfill, int* __restrict__ colids,
                               int E, int span) {
    const int r = blockIdx.x & 7;
    const int chunk = blockIdx.x >> 3;
    const int nchunks = gridDim.x >> 3;
    const int lo = r * span, hi = lo + span;
    const int per = (E + nchunks - 1) / nchunks;
    const int e1 = min(E, (chunk + 1) * per);
    for (int e = chunk * per + threadIdx.x; e < e1; e += blockDim.x) {
        int d = dst[e];
        if (d >= lo && d < hi) {
            int pos = atomicAdd(&nfill[d], 1);
            colids[rowptr[d] + pos] = e;
        }
    }
}

__global__ void k_scan1(const int* __restrict__ counts, int* __restrict__ incl,
                        int* __restrict__ partial, int n) {
    __shared__ int tmp[1024];
    int tid = threadIdx.x, base = blockIdx.x * 1024;
    int v = (base + tid < n) ? counts[base + tid] : 0;
    tmp[tid] = v;
    __syncthreads();
    for (int off = 1; off < 1024; off <<= 1) {
        int t = (tid >= off) ? tmp[tid - off] : 0;
        __syncthreads();
        tmp[tid] += t;
        __syncthreads();
    }
    if (base + tid < n) incl[base + tid] = tmp[tid];
    if (tid == 1023) partial[blockIdx.x] = tmp[1023];
}

// exclusive rowptr = block-base + incl - counts; zeroes nfill; writes rowptr[n].
__global__ void k_scan3(const int* __restrict__ counts, const int* __restrict__ incl,
                        const int* __restrict__ partial, int* __restrict__ rowptr,
                        int* __restrict__ nfill, int n, int nb) {
    __shared__ int sbase;
    if (threadIdx.x == 0) {
        int b = 0;
        for (int p = 0; p < (int)blockIdx.x; ++p) b += partial[p];
        sbase = b;
        if ((int)blockIdx.x == nb - 1) {
            int tot = b;
            for (int p = blockIdx.x; p < nb; ++p) tot += partial[p];
            rowptr[n] = tot;
        }
    }
    __syncthreads();
    int i = blockIdx.x * 1024 + threadIdx.x;
    if (i < n) {
        rowptr[i] = sbase + incl[i] - counts[i];
        nfill[i] = 0;
    }
}

__global__ void k_sort(const int* __restrict__ rowptr, const int* __restrict__ colids,
                       const int* __restrict__ esrc, int* __restrict__ colsrc, int n) {
    int node = blockIdx.x * 4 + (threadIdx.x >> 6);
    int lane = threadIdx.x & 63;
    if (node >= n) return;
    int s = rowptr[node], e = rowptr[node + 1];
    int d = e - s;
    if (d <= 0) return;
    if (d <= 64) {
        int v = (lane < d) ? colids[s + lane] : INT_MAX;
        int rank = 0;
        for (int j = 0; j < d; ++j) {
            int vj = __shfl(v, j, 64);
            rank += (vj < v) ? 1 : 0;
        }
        if (lane < d) colsrc[s + rank] = esrc[v];
    } else {
        if (lane == 0) {
            int last = -1;
            for (int k = 0; k < d; ++k) {
                int best = INT_MAX;
                for (int j = s; j < e; ++j) {
                    int id = colids[j];
                    if (id > last && id < best) best = id;
                }
                colsrc[s + k] = esrc[best];
                last = best;
            }
        }
    }
}

// ---- W prep (all 4 layers, one launch): fp32 Wl|Wr -> fp16 fragment-ordered ----

struct WprepArgs {
    const float* Wl[4];
    const float* Wr[4];
    __half* Wz[4];
};

__global__ void k_wprep_all(WprepArgs a) {
    int b = blockIdx.x;
    int layer = (b < 16) ? 0 : (b < 32) ? 1 : (b < 48) ? 2 : 3;
    int base = layer * 16;
    int HC = (layer == 3) ? 64 : 128;
    int NT = 2 * HC / 16;
    int tid = (b - base) * 256 + threadIdx.x;
    int l = tid & 63, c = tid >> 6;
    int ks = c / NT, nt = c % NT;
    int col = nt * 16 + (l & 15);
    int kbase = ks * 32 + ((l >> 4) << 3);
    const float* W = (col < HC) ? (a.Wl[layer] + col) : (a.Wr[layer] + (col - HC));
    __half h[8];
#pragma unroll
    for (int j = 0; j < 8; ++j) h[j] = __float2half(W[(size_t)(kbase + j) * HC]);
    *(uint4*)&a.Wz[layer][(size_t)tid * 8] = *(const uint4*)h;
}

// ---- MFMA GEMM: [n x 128] @ [128 x 2*HC](fp16) -> xl fp16 | xr fp32 ----

template <int HC, bool CVT>
__global__ void __launch_bounds__(256) k_gemm_mfma(
        const void* __restrict__ Ain, const __half* __restrict__ Wz,
        __half* __restrict__ xl, float* __restrict__ xr, int n) {
    constexpr int NT = 2 * HC / 16;
    const int l = threadIdx.x & 63;
    const int wid = threadIdx.x >> 6;
    const int r0 = (blockIdx.x * 4 + wid) * 16;
    if (r0 >= n) return;
    const int m = l & 15, kb = l >> 4;
    const int ra = min(r0 + m, n - 1);
    const f16x8* Bz = (const f16x8*)Wz;

    f32x4 acc[NT];
#pragma unroll
    for (int nt = 0; nt < NT; ++nt) acc[nt] = (f32x4){0.f, 0.f, 0.f, 0.f};

#pragma unroll
    for (int ks = 0; ks < 4; ++ks) {
        f16x8 a;
        if (CVT) {
            const float* Af = (const float*)Ain + (size_t)ra * FIN + kb * 8 + ks * 32;
            float4 f0 = *(const float4*)Af;
            float4 f1 = *(const float4*)(Af + 4);
            a[0] = (_Float16)f0.x; a[1] = (_Float16)f0.y;
            a[2] = (_Float16)f0.z; a[3] = (_Float16)f0.w;
            a[4] = (_Float16)f1.x; a[5] = (_Float16)f1.y;
            a[6] = (_Float16)f1.z; a[7] = (_Float16)f1.w;
        } else {
            a = *(const f16x8*)((const _Float16*)Ain + (size_t)ra * FIN + kb * 8 + ks * 32);
        }
#pragma unroll
        for (int nt = 0; nt < NT; ++nt) {
            f16x8 b = Bz[(ks * NT + nt) * 64 + l];
            acc[nt] = __builtin_amdgcn_mfma_f32_16x16x32_f16(a, b, acc[nt], 0, 0, 0);
        }
    }

    const int rb = r0 + kb * 4;
#pragma unroll
    for (int nt = 0; nt < NT; ++nt) {
        int c = nt * 16 + m;
        if (nt < NT / 2) {
#pragma unroll
            for (int r = 0; r < 4; ++r) {
                int row = rb + r;
                if (row < n) xl[(size_t)row * HC + c] = __float2half(acc[nt][r]);
            }
        } else {
            int cd = c - HC;
#pragma unroll
            for (int r = 0; r < 4; ++r) {
                int row = rb + r;
                if (row < n) xr[(size_t)row * HC + cd] = acc[nt][r];
            }
        }
    }
}

// ------- fused attention H=2: 16 lanes/edge (8 ch each), 8 edges/round -------
// No-max softmax; 2-round-deep gather pipeline; unclamped indices (+64 pad).

template <bool RELU>
__global__ void __launch_bounds__(256) k_fused2(
        const __half* __restrict__ xlh, const float* __restrict__ xr,
        const int* __restrict__ rowptr, const int* __restrict__ colsrc,
        const float* __restrict__ attc, const float* __restrict__ bias,
        __half* __restrict__ out, int N) {
    const int lane = threadIdx.x & 63;
    const int g = lane >> 4;
    const int s = lane & 15;
    const int c0 = s * 8;
    int i = blockIdx.x * 4 + (threadIdx.x >> 6);
    const int stride = gridDim.x * 4;
    const float L2E = 1.4426950408889634f;

    f32x2 a6[4], a4[4];
    {
        float4 a0 = *(const float4*)&attc[c0];
        float4 a1 = *(const float4*)&attc[c0 + 4];
        float t[8] = {a0.x, a0.y, a0.z, a0.w, a1.x, a1.y, a1.z, a1.w};
#pragma unroll
        for (int k = 0; k < 4; ++k) {
            a6[k] = (f32x2){0.6f * L2E * t[2 * k], 0.6f * L2E * t[2 * k + 1]};
            a4[k] = (f32x2){0.4f * L2E * t[2 * k], 0.4f * L2E * t[2 * k + 1]};
        }
    }

    for (; i < N; i += stride) {
        f32x2 xrv[4];
        {
            float4 r0 = *(const float4*)&xr[(size_t)i * 128 + c0];
            float4 r1 = *(const float4*)&xr[(size_t)i * 128 + c0 + 4];
            xrv[0] = (f32x2){r0.x, r0.y}; xrv[1] = (f32x2){r0.z, r0.w};
            xrv[2] = (f32x2){r1.x, r1.y}; xrv[3] = (f32x2){r1.z, r1.w};
        }
        const int st = rowptr[i], en = rowptr[i + 1];
        float den = 0.f;
        f32x2 acc[4];
#pragma unroll
        for (int k = 0; k < 4; ++k) acc[k] = (f32x2){0.f, 0.f};

        if (st < en) {
            uint4 w0 = *(const uint4*)(xlh + ((size_t)colsrc[st + g] << 7) + c0);
            uint4 w1 = *(const uint4*)(xlh + ((size_t)colsrc[st + 4 + g] << 7) + c0);
            uint4 w2 = *(const uint4*)(xlh + ((size_t)colsrc[st + 8 + g] << 7) + c0);
            uint4 w3 = *(const uint4*)(xlh + ((size_t)colsrc[st + 12 + g] << 7) + c0);
            int i0 = colsrc[st + 16 + g];
            int i1 = colsrc[st + 20 + g];
            for (int j = st; j < en; j += 8) {
                uint4 n0 = *(const uint4*)(xlh + ((size_t)i0 << 7) + c0);
                uint4 n1 = *(const uint4*)(xlh + ((size_t)i1 << 7) + c0);
                i0 = colsrc[j + 24 + g];
                i1 = colsrc[j + 28 + g];

#pragma unroll
                for (int q = 0; q < 2; ++q) {
                    const uint4 w = q ? w1 : w0;
                    f32x2 xv[4];
                    xv[0] = h2f2x(w.x); xv[1] = h2f2x(w.y);
                    xv[2] = h2f2x(w.z); xv[3] = h2f2x(w.w);
                    f32x2 sc = (f32x2){0.f, 0.f};
#pragma unroll
                    for (int k = 0; k < 4; ++k) {
                        f32x2 u = pk_add(xv[k], xrv[k]);
                        sc = pk_fma(u, a6[k], sc);
                        f32x2 ua = {__builtin_fabsf(u.x), __builtin_fabsf(u.y)};
                        sc = pk_fma(ua, a4[k], sc);
                    }
                    float p = reduce8_dpp(sc.x + sc.y);
                    p = (j + q * 4 + g < en) ? p : -INFINITY;   // exp2(-inf)=0
                    float pe = exp2f(p);
                    den += pe;
                    f32x2 pe2 = (f32x2){pe, pe};
#pragma unroll
                    for (int k = 0; k < 4; ++k) acc[k] = pk_fma(pe2, xv[k], acc[k]);
                }
                w0 = w2; w1 = w3; w2 = n0; w3 = n1;
            }
        }

        // merge the 4 edge groups: plain butterfly adds
#pragma unroll
        for (int off = 16; off <= 32; off <<= 1) {
            den += __shfl_xor(den, off, 64);
#pragma unroll
            for (int k = 0; k < 4; ++k) {
                acc[k].x += __shfl_xor(acc[k].x, off, 64);
                acc[k].y += __shfl_xor(acc[k].y, off, 64);
            }
        }

        if (g == 0) {
            float4 b0 = *(const float4*)&bias[c0];
            float4 b1 = *(const float4*)&bias[c0 + 4];
            float bv[8] = {b0.x, b0.y, b0.z, b0.w, b1.x, b1.y, b1.z, b1.w};
            float inv = 1.f / (den + 1e-16f);
            __half hb[8];
#pragma unroll
            for (int k = 0; k < 8; ++k) {
                float av = (k & 1) ? acc[k >> 1].y : acc[k >> 1].x;
                float o = fmaf(av, inv, bv[k]);
                if (RELU) o = fmaxf(o, 0.f);
                hb[k] = __float2half(o);
            }
            *(uint4*)&out[(size_t)i * 128 + c0] = *(const uint4*)hb;
        }
    }
}

// ------- fused attention H=1 (layer 4): 8 lanes/edge, 16 edges/round, no-max -------

__global__ void __launch_bounds__(256) k_fused1(
        const __half* __restrict__ xlh, const float* __restrict__ xr,
        const int* __restrict__ rowptr, const int* __restrict__ colsrc,
        const float* __restrict__ attc, const float* __restrict__ bias,
        float* __restrict__ out, int N) {
    const int lane = threadIdx.x & 63;
    const int g = lane >> 3;
    const int s = lane & 7;
    const int c0 = s * 8;
    int i = blockIdx.x * 4 + (threadIdx.x >> 6);
    const int stride = gridDim.x * 4;
    const float L2E = 1.4426950408889634f;

    f32x2 a6[4], a4[4];
    {
        float4 a0 = *(const float4*)&attc[c0];
        float4 a1 = *(const float4*)&attc[c0 + 4];
        float t[8] = {a0.x, a0.y, a0.z, a0.w, a1.x, a1.y, a1.z, a1.w};
#pragma unroll
        for (int k = 0; k < 4; ++k) {
            a6[k] = (f32x2){0.6f * L2E * t[2 * k], 0.6f * L2E * t[2 * k + 1]};
            a4[k] = (f32x2){0.4f * L2E * t[2 * k], 0.4f * L2E * t[2 * k + 1]};
        }
    }

    for (; i < N; i += stride) {
        f32x2 xrv[4];
        {
            float4 r0 = *(const float4*)&xr[(size_t)i * 64 + c0];
            float4 r1 = *(const float4*)&xr[(size_t)i * 64 + c0 + 4];
            xrv[0] = (f32x2){r0.x, r0.y}; xrv[1] = (f32x2){r0.z, r0.w};
            xrv[2] = (f32x2){r1.x, r1.y}; xrv[3] = (f32x2){r1.z, r1.w};
        }
        const int st = rowptr[i], en = rowptr[i + 1];
        float den = 0.f;
        f32x2 acc[4];
#pragma unroll
        for (int k = 0; k < 4; ++k) acc[k] = (f32x2){0.f, 0.f};

        if (st < en) {
            uint4 w0 = *(const uint4*)(xlh + ((size_t)colsrc[st + g] << 6) + c0);
            uint4 w1 = *(const uint4*)(xlh + ((size_t)colsrc[st + 8 + g] << 6) + c0);
            int i0 = colsrc[st + 16 + g];
            int i1 = colsrc[st + 24 + g];
            for (int j = st; j < en; j += 16) {
                uint4 n0 = *(const uint4*)(xlh + ((size_t)i0 << 6) + c0);
                uint4 n1 = *(const uint4*)(xlh + ((size_t)i1 << 6) + c0);
                i0 = colsrc[j + 32 + g];
                i1 = colsrc[j + 40 + g];

#pragma unroll
                for (int q = 0; q < 2; ++q) {
                    const uint4 w = q ? w1 : w0;
                    f32x2 xv[4];
                    xv[0] = h2f2x(w.x); xv[1] = h2f2x(w.y);
                    xv[2] = h2f2x(w.z); xv[3] = h2f2x(w.w);
                    f32x2 sc = (f32x2){0.f, 0.f};
#pragma unroll
                    for (int k = 0; k < 4; ++k) {
                        f32x2 u = pk_add(xv[k], xrv[k]);
                        sc = pk_fma(u, a6[k], sc);
                        f32x2 ua = {__builtin_fabsf(u.x), __builtin_fabsf(u.y)};
                        sc = pk_fma(ua, a4[k], sc);
                    }
                    float p = reduce8_dpp(sc.x + sc.y);
                    p = (j + q * 8 + g < en) ? p : -INFINITY;
                    float pe = exp2f(p);
                    den += pe;
                    f32x2 pe2 = (f32x2){pe, pe};
#pragma unroll
                    for (int k = 0; k < 4; ++k) acc[k] = pk_fma(pe2, xv[k], acc[k]);
                }
                w0 = n0; w1 = n1;
            }
        }

        // merge the 8 edge groups
#pragma unroll
        for (int off = 8; off <= 32; off <<= 1) {
            den += __shfl_xor(den, off, 64);
#pragma unroll
            for (int k = 0; k < 4; ++k) {
                acc[k].x += __shfl_xor(acc[k].x, off, 64);
                acc[k].y += __shfl_xor(acc[k].y, off, 64);
            }
        }

        if (g == 0) {
            float4 b0 = *(const float4*)&bias[c0];
            float4 b1 = *(const float4*)&bias[c0 + 4];
            float bv[8] = {b0.x, b0.y, b0.z, b0.w, b1.x, b1.y, b1.z, b1.w};
            float inv = 1.f / (den + 1e-16f);
            float o[8];
#pragma unroll
            for (int k = 0; k < 8; ++k) {
                float av = (k & 1) ? acc[k >> 1].y : acc[k >> 1].x;
                o[k] = fmaf(av, inv, bv[k]);
            }
            *(float4*)&out[(size_t)i * 64 + c0] = make_float4(o[0], o[1], o[2], o[3]);
            *(float4*)&out[(size_t)i * 64 + c0 + 4] = make_float4(o[4], o[5], o[6], o[7]);
        }
    }
}

// ---------------- launch ----------------

static inline size_t align_up(size_t v, size_t a) { return (v + a - 1) & ~(a - 1); }

extern "C" void kernel_launch(void* const* d_in, const int* in_sizes, int n_in,
                              void* d_out, int out_size, void* d_ws, size_t ws_size,
                              hipStream_t stream) {
    const float* x = (const float*)d_in[0];
    const int* ei = (const int*)d_in[1];
    const int N = in_sizes[0] / FIN;
    const int E = in_sizes[1] / 2;
    const int* esrc = ei;
    const int* edst = ei + E;

    const float* Wl1 = (const float*)d_in[2];
    const float* Wr1 = (const float*)d_in[3];
    const float* att1 = (const float*)d_in[4];
    const float* b1 = (const float*)d_in[5];
    const float* Wl2 = (const float*)d_in[6];
    const float* Wr2 = (const float*)d_in[7];
    const float* att2 = (const float*)d_in[8];
    const float* b2 = (const float*)d_in[9];
    const float* Wl3 = (const float*)d_in[10];
    const float* Wr3 = (const float*)d_in[11];
    const float* att3 = (const float*)d_in[12];
    const float* b3 = (const float*)d_in[13];
    const float* Wl4 = (const float*)d_in[14];
    const float* Wr4 = (const float*)d_in[15];
    const float* att4 = (const float*)d_in[16];
    const float* b4 = (const float*)d_in[17];

    const int nb = (N + 1023) / 1024;
    const int span = (N + 7) / 8;

    size_t off = 0;
    char* w = (char*)d_ws;
    auto alloc = [&](size_t bytes) {
        char* p = w + off;
        off = align_up(off + bytes, 256);
        return p;
    };
    int* rowptr = (int*)alloc((size_t)(N + 1) * 4);
    int* nfill = (int*)alloc((size_t)N * 4);
    int* incl = (int*)alloc((size_t)N * 4);
    int* partial = (int*)alloc(1024 * 4);
    int* colids = (int*)alloc((size_t)E * 4);
    int* colsrc = (int*)alloc((size_t)(E + 64) * 4);   // +64 zero pad: unclamped prefetch
    __half* xb16 = (__half*)alloc((size_t)N * FIN * 2);
    __half* xlh = (__half*)alloc((size_t)N * FIN * 2);
    float* xr = (float*)alloc((size_t)N * FIN * 4);
    __half* Wz1 = (__half*)alloc(65536);
    __half* Wz2 = (__half*)alloc(65536);
    __half* Wz3 = (__half*)alloc(65536);
    __half* Wz4 = (__half*)alloc(32768);
    if (off > ws_size) return;

    // CSR build (deterministic: per-node lists sorted by edge id)
    hipMemsetAsync(nfill, 0, (size_t)N * 4, stream);
    hipMemsetAsync(colsrc + E, 0, 64 * 4, stream);
    k_hist_part<<<256, 256, 0, stream>>>(edst, nfill, E, span);
    k_scan1<<<nb, 1024, 0, stream>>>(nfill, incl, partial, N);
    k_scan3<<<nb, 1024, 0, stream>>>(nfill, incl, partial, rowptr, nfill, N, nb);
    k_scatter_part<<<256, 256, 0, stream>>>(edst, rowptr, nfill, colids, E, span);
    k_sort<<<(N + 3) / 4, 256, 0, stream>>>(rowptr, colids, esrc, colsrc, N);

    // weight prep (all layers, one launch)
    WprepArgs wa;
    wa.Wl[0] = Wl1; wa.Wl[1] = Wl2; wa.Wl[2] = Wl3; wa.Wl[3] = Wl4;
    wa.Wr[0] = Wr1; wa.Wr[1] = Wr2; wa.Wr[2] = Wr3; wa.Wr[3] = Wr4;
    wa.Wz[0] = Wz1; wa.Wz[1] = Wz2; wa.Wz[2] = Wz3; wa.Wz[3] = Wz4;
    k_wprep_all<<<56, 256, 0, stream>>>(wa);

    const int gg = (N + 63) / 64;
    const int gf = (N + 3) / 4;   // 1 node per wave: fine-grained tail backfill

    k_gemm_mfma<128, true><<<gg, 256, 0, stream>>>(x, Wz1, xlh, xr, N);
    k_fused2<true><<<gf, 256, 0, stream>>>(xlh, xr, rowptr, colsrc, att1, b1, xb16, N);
    k_gemm_mfma<128, false><<<gg, 256, 0, stream>>>(xb16, Wz2, xlh, xr, N);
    k_fused2<true><<<gf, 256, 0, stream>>>(xlh, xr, rowptr, colsrc, att2, b2, xb16, N);
    k_gemm_mfma<128, false><<<gg, 256, 0, stream>>>(xb16, Wz3, xlh, xr, N);
    k_fused2<true><<<gf, 256, 0, stream>>>(xlh, xr, rowptr, colsrc, att3, b3, xb16, N);
    k_gemm_mfma<64, false><<<gg, 256, 0, stream>>>(xb16, Wz4, xlh, xr, N);
    k_fused1<<<gf, 256, 0, stream>>>(xlh, xr, rowptr, colsrc, att4, b4, (float*)d_out, N);
}

// Round 12
// 385.506 us; speedup vs baseline: 1.1121x; 1.1121x over previous
//
#include <hip/hip_runtime.h>
#include <hip/hip_fp16.h>
#include <math.h>
#include <limits.h>

#define FIN 128
#define NEG_SLOPE 0.2f

typedef _Float16 f16x8 __attribute__((ext_vector_type(8)));
typedef float f32x4 __attribute__((ext_vector_type(4)));
typedef float f32x2 __attribute__((ext_vector_type(2)));

// ---- VOP3P packed fp32 (CDNA dual-FP32). hipcc never auto-forms these. ----
static __device__ __forceinline__ f32x2 pk_add(f32x2 a, f32x2 b) {
    f32x2 d; asm("v_pk_add_f32 %0, %1, %2" : "=v"(d) : "v"(a), "v"(b)); return d;
}
static __device__ __forceinline__ f32x2 pk_fma(f32x2 a, f32x2 b, f32x2 c) {
    f32x2 d; asm("v_pk_fma_f32 %0, %1, %2, %3" : "=v"(d) : "v"(a), "v"(b), "v"(c)); return d;
}

static __device__ __forceinline__ f32x2 h2f2x(unsigned int u) {
    __half2 h = *reinterpret_cast<__half2*>(&u);
    float2 f = __half22float2(h);
    return (f32x2){f.x, f.y};
}

// DPP tree-add within 8-lane groups (xor1, xor2, xor4). Full-rate VALU, no LDS.
template <int CTRL>
static __device__ __forceinline__ float dpp_add(float x) {
    int t = __builtin_amdgcn_update_dpp(0, __builtin_bit_cast(int, x), CTRL, 0xF, 0xF, true);
    return x + __builtin_bit_cast(float, t);
}
static __device__ __forceinline__ float reduce8_dpp(float p) {
    p = dpp_add<0xB1>(p);    // quad_perm [1,0,3,2]  : xor 1
    p = dpp_add<0x4E>(p);    // quad_perm [2,3,0,1]  : xor 2
    p = dpp_add<0x141>(p);   // row_half_mirror      : xor 4
    return p;
}

// ---------------- CSR build (XCD-range-partitioned hist/scatter) ----------------
// range = blockIdx & 7 (consistent XCD round-robin): all atomics/writes for one
// node-range stay in one XCD's L2 -> dense writeback. 2048 blocks = 256 chunks
// per range (R11 used 256 total blocks -> 10% occupancy; parallelism restored).

__global__ void k_hist_part(const int* __restrict__ dst, int* __restrict__ counts,
                            int E, int span) {
    const int r = blockIdx.x & 7;
    const int chunk = blockIdx.x >> 3;
    const int nchunks = gridDim.x >> 3;
    const int lo = r * span, hi = lo + span;
    const int per = (E + nchunks - 1) / nchunks;
    const int e1 = min(E, (chunk + 1) * per);
    for (int e = chunk * per + threadIdx.x; e < e1; e += blockDim.x) {
        int d = dst[e];
        if (d >= lo && d < hi) atomicAdd(&counts[d], 1);
    }
}

__global__ void k_scatter_part(const int* __restrict__ dst, const int* __restrict__ rowptr,
                               int* __restrict__ nfill, int* __restrict__ colids,
                               int E, int span) {
    const int r = blockIdx.x & 7;
    const int chunk = blockIdx.x >> 3;
    const int nchunks = gridDim.x >> 3;
    const int lo = r * span, hi = lo + span;
    const int per = (E + nchunks - 1) / nchunks;
    const int e1 = min(E, (chunk + 1) * per);
    for (int e = chunk * per + threadIdx.x; e < e1; e += blockDim.x) {
        int d = dst[e];
        if (d >= lo && d < hi) {
            int pos = atomicAdd(&nfill[d], 1);
            colids[rowptr[d] + pos] = e;
        }
    }
}

__global__ void k_scan1(const int* __restrict__ counts, int* __restrict__ incl,
                        int* __restrict__ partial, int n) {
    __shared__ int tmp[1024];
    int tid = threadIdx.x, base = blockIdx.x * 1024;
    int v = (base + tid < n) ? counts[base + tid] : 0;
    tmp[tid] = v;
    __syncthreads();
    for (int off = 1; off < 1024; off <<= 1) {
        int t = (tid >= off) ? tmp[tid - off] : 0;
        __syncthreads();
        tmp[tid] += t;
        __syncthreads();
    }
    if (base + tid < n) incl[base + tid] = tmp[tid];
    if (tid == 1023) partial[blockIdx.x] = tmp[1023];
}

// exclusive rowptr = block-base + incl - counts; zeroes nfill; writes rowptr[n].
__global__ void k_scan3(const int* __restrict__ counts, const int* __restrict__ incl,
                        const int* __restrict__ partial, int* __restrict__ rowptr,
                        int* __restrict__ nfill, int n, int nb) {
    __shared__ int sbase;
    if (threadIdx.x == 0) {
        int b = 0;
        for (int p = 0; p < (int)blockIdx.x; ++p) b += partial[p];
        sbase = b;
        if ((int)blockIdx.x == nb - 1) {
            int tot = b;
            for (int p = blockIdx.x; p < nb; ++p) tot += partial[p];
            rowptr[n] = tot;
        }
    }
    __syncthreads();
    int i = blockIdx.x * 1024 + threadIdx.x;
    if (i < n) {
        rowptr[i] = sbase + incl[i] - counts[i];
        nfill[i] = 0;
    }
}

__global__ void k_sort(const int* __restrict__ rowptr, const int* __restrict__ colids,
                       const int* __restrict__ esrc, int* __restrict__ colsrc, int n) {
    int node = blockIdx.x * 4 + (threadIdx.x >> 6);
    int lane = threadIdx.x & 63;
    if (node >= n) return;
    int s = rowptr[node], e = rowptr[node + 1];
    int d = e - s;
    if (d <= 0) return;
    if (d <= 64) {
        int v = (lane < d) ? colids[s + lane] : INT_MAX;
        int rank = 0;
        for (int j = 0; j < d; ++j) {
            int vj = __shfl(v, j, 64);
            rank += (vj < v) ? 1 : 0;
        }
        if (lane < d) colsrc[s + rank] = esrc[v];
    } else {
        if (lane == 0) {
            int last = -1;
            for (int k = 0; k < d; ++k) {
                int best = INT_MAX;
                for (int j = s; j < e; ++j) {
                    int id = colids[j];
                    if (id > last && id < best) best = id;
                }
                colsrc[s + k] = esrc[best];
                last = best;
            }
        }
    }
}

// ---- W prep (all 4 layers, one launch): fp32 Wl|Wr -> fp16 fragment-ordered ----

struct WprepArgs {
    const float* Wl[4];
    const float* Wr[4];
    __half* Wz[4];
};

__global__ void k_wprep_all(WprepArgs a) {
    int b = blockIdx.x;
    int layer = (b < 16) ? 0 : (b < 32) ? 1 : (b < 48) ? 2 : 3;
    int base = layer * 16;
    int HC = (layer == 3) ? 64 : 128;
    int NT = 2 * HC / 16;
    int tid = (b - base) * 256 + threadIdx.x;
    int l = tid & 63, c = tid >> 6;
    int ks = c / NT, nt = c % NT;
    int col = nt * 16 + (l & 15);
    int kbase = ks * 32 + ((l >> 4) << 3);
    const float* W = (col < HC) ? (a.Wl[layer] + col) : (a.Wr[layer] + (col - HC));
    __half h[8];
#pragma unroll
    for (int j = 0; j < 8; ++j) h[j] = __float2half(W[(size_t)(kbase + j) * HC]);
    *(uint4*)&a.Wz[layer][(size_t)tid * 8] = *(const uint4*)h;
}

// ---- MFMA GEMM: [n x 128] @ [128 x 2*HC](fp16) -> xl fp16 | xr fp32 ----

template <int HC, bool CVT>
__global__ void __launch_bounds__(256) k_gemm_mfma(
        const void* __restrict__ Ain, const __half* __restrict__ Wz,
        __half* __restrict__ xl, float* __restrict__ xr, int n) {
    constexpr int NT = 2 * HC / 16;
    const int l = threadIdx.x & 63;
    const int wid = threadIdx.x >> 6;
    const int r0 = (blockIdx.x * 4 + wid) * 16;
    if (r0 >= n) return;
    const int m = l & 15, kb = l >> 4;
    const int ra = min(r0 + m, n - 1);
    const f16x8* Bz = (const f16x8*)Wz;

    f32x4 acc[NT];
#pragma unroll
    for (int nt = 0; nt < NT; ++nt) acc[nt] = (f32x4){0.f, 0.f, 0.f, 0.f};

#pragma unroll
    for (int ks = 0; ks < 4; ++ks) {
        f16x8 a;
        if (CVT) {
            const float* Af = (const float*)Ain + (size_t)ra * FIN + kb * 8 + ks * 32;
            float4 f0 = *(const float4*)Af;
            float4 f1 = *(const float4*)(Af + 4);
            a[0] = (_Float16)f0.x; a[1] = (_Float16)f0.y;
            a[2] = (_Float16)f0.z; a[3] = (_Float16)f0.w;
            a[4] = (_Float16)f1.x; a[5] = (_Float16)f1.y;
            a[6] = (_Float16)f1.z; a[7] = (_Float16)f1.w;
        } else {
            a = *(const f16x8*)((const _Float16*)Ain + (size_t)ra * FIN + kb * 8 + ks * 32);
        }
#pragma unroll
        for (int nt = 0; nt < NT; ++nt) {
            f16x8 b = Bz[(ks * NT + nt) * 64 + l];
            acc[nt] = __builtin_amdgcn_mfma_f32_16x16x32_f16(a, b, acc[nt], 0, 0, 0);
        }
    }

    const int rb = r0 + kb * 4;
#pragma unroll
    for (int nt = 0; nt < NT; ++nt) {
        int c = nt * 16 + m;
        if (nt < NT / 2) {
#pragma unroll
            for (int r = 0; r < 4; ++r) {
                int row = rb + r;
                if (row < n) xl[(size_t)row * HC + c] = __float2half(acc[nt][r]);
            }
        } else {
            int cd = c - HC;
#pragma unroll
            for (int r = 0; r < 4; ++r) {
                int row = rb + r;
                if (row < n) xr[(size_t)row * HC + cd] = acc[nt][r];
            }
        }
    }
}

// ------- fused attention H=2: 16 lanes/edge (8 ch each), 8 edges/round -------
// No-max softmax; 2-round-deep gather pipeline; unclamped indices (+64 pad).

template <bool RELU>
__global__ void __launch_bounds__(256) k_fused2(
        const __half* __restrict__ xlh, const float* __restrict__ xr,
        const int* __restrict__ rowptr, const int* __restrict__ colsrc,
        const float* __restrict__ attc, const float* __restrict__ bias,
        __half* __restrict__ out, int N) {
    const int lane = threadIdx.x & 63;
    const int g = lane >> 4;
    const int s = lane & 15;
    const int c0 = s * 8;
    int i = blockIdx.x * 4 + (threadIdx.x >> 6);
    const int stride = gridDim.x * 4;
    const float L2E = 1.4426950408889634f;

    f32x2 a6[4], a4[4];
    {
        float4 a0 = *(const float4*)&attc[c0];
        float4 a1 = *(const float4*)&attc[c0 + 4];
        float t[8] = {a0.x, a0.y, a0.z, a0.w, a1.x, a1.y, a1.z, a1.w};
#pragma unroll
        for (int k = 0; k < 4; ++k) {
            a6[k] = (f32x2){0.6f * L2E * t[2 * k], 0.6f * L2E * t[2 * k + 1]};
            a4[k] = (f32x2){0.4f * L2E * t[2 * k], 0.4f * L2E * t[2 * k + 1]};
        }
    }

    for (; i < N; i += stride) {
        f32x2 xrv[4];
        {
            float4 r0 = *(const float4*)&xr[(size_t)i * 128 + c0];
            float4 r1 = *(const float4*)&xr[(size_t)i * 128 + c0 + 4];
            xrv[0] = (f32x2){r0.x, r0.y}; xrv[1] = (f32x2){r0.z, r0.w};
            xrv[2] = (f32x2){r1.x, r1.y}; xrv[3] = (f32x2){r1.z, r1.w};
        }
        const int st = rowptr[i], en = rowptr[i + 1];
        float den = 0.f;
        f32x2 acc[4];
#pragma unroll
        for (int k = 0; k < 4; ++k) acc[k] = (f32x2){0.f, 0.f};

        if (st < en) {
            uint4 w0 = *(const uint4*)(xlh + ((size_t)colsrc[st + g] << 7) + c0);
            uint4 w1 = *(const uint4*)(xlh + ((size_t)colsrc[st + 4 + g] << 7) + c0);
            uint4 w2 = *(const uint4*)(xlh + ((size_t)colsrc[st + 8 + g] << 7) + c0);
            uint4 w3 = *(const uint4*)(xlh + ((size_t)colsrc[st + 12 + g] << 7) + c0);
            int i0 = colsrc[st + 16 + g];
            int i1 = colsrc[st + 20 + g];
            for (int j = st; j < en; j += 8) {
                uint4 n0 = *(const uint4*)(xlh + ((size_t)i0 << 7) + c0);
                uint4 n1 = *(const uint4*)(xlh + ((size_t)i1 << 7) + c0);
                i0 = colsrc[j + 24 + g];
                i1 = colsrc[j + 28 + g];

#pragma unroll
                for (int q = 0; q < 2; ++q) {
                    const uint4 w = q ? w1 : w0;
                    f32x2 xv[4];
                    xv[0] = h2f2x(w.x); xv[1] = h2f2x(w.y);
                    xv[2] = h2f2x(w.z); xv[3] = h2f2x(w.w);
                    f32x2 sc = (f32x2){0.f, 0.f};
#pragma unroll
                    for (int k = 0; k < 4; ++k) {
                        f32x2 u = pk_add(xv[k], xrv[k]);
                        sc = pk_fma(u, a6[k], sc);
                        f32x2 ua = {__builtin_fabsf(u.x), __builtin_fabsf(u.y)};
                        sc = pk_fma(ua, a4[k], sc);
                    }
                    float p = reduce8_dpp(sc.x + sc.y);
                    p = (j + q * 4 + g < en) ? p : -INFINITY;   // exp2(-inf)=0
                    float pe = exp2f(p);
                    den += pe;
                    f32x2 pe2 = (f32x2){pe, pe};
#pragma unroll
                    for (int k = 0; k < 4; ++k) acc[k] = pk_fma(pe2, xv[k], acc[k]);
                }
                w0 = w2; w1 = w3; w2 = n0; w3 = n1;
            }
        }

        // merge the 4 edge groups: plain butterfly adds
#pragma unroll
        for (int off = 16; off <= 32; off <<= 1) {
            den += __shfl_xor(den, off, 64);
#pragma unroll
            for (int k = 0; k < 4; ++k) {
                acc[k].x += __shfl_xor(acc[k].x, off, 64);
                acc[k].y += __shfl_xor(acc[k].y, off, 64);
            }
        }

        if (g == 0) {
            float4 b0 = *(const float4*)&bias[c0];
            float4 b1 = *(const float4*)&bias[c0 + 4];
            float bv[8] = {b0.x, b0.y, b0.z, b0.w, b1.x, b1.y, b1.z, b1.w};
            float inv = 1.f / (den + 1e-16f);
            __half hb[8];
#pragma unroll
            for (int k = 0; k < 8; ++k) {
                float av = (k & 1) ? acc[k >> 1].y : acc[k >> 1].x;
                float o = fmaf(av, inv, bv[k]);
                if (RELU) o = fmaxf(o, 0.f);
                hb[k] = __float2half(o);
            }
            *(uint4*)&out[(size_t)i * 128 + c0] = *(const uint4*)hb;
        }
    }
}

// ------- fused attention H=1 (layer 4): 8 lanes/edge, 16 edges/round, no-max -------

__global__ void __launch_bounds__(256) k_fused1(
        const __half* __restrict__ xlh, const float* __restrict__ xr,
        const int* __restrict__ rowptr, const int* __restrict__ colsrc,
        const float* __restrict__ attc, const float* __restrict__ bias,
        float* __restrict__ out, int N) {
    const int lane = threadIdx.x & 63;
    const int g = lane >> 3;
    const int s = lane & 7;
    const int c0 = s * 8;
    int i = blockIdx.x * 4 + (threadIdx.x >> 6);
    const int stride = gridDim.x * 4;
    const float L2E = 1.4426950408889634f;

    f32x2 a6[4], a4[4];
    {
        float4 a0 = *(const float4*)&attc[c0];
        float4 a1 = *(const float4*)&attc[c0 + 4];
        float t[8] = {a0.x, a0.y, a0.z, a0.w, a1.x, a1.y, a1.z, a1.w};
#pragma unroll
        for (int k = 0; k < 4; ++k) {
            a6[k] = (f32x2){0.6f * L2E * t[2 * k], 0.6f * L2E * t[2 * k + 1]};
            a4[k] = (f32x2){0.4f * L2E * t[2 * k], 0.4f * L2E * t[2 * k + 1]};
        }
    }

    for (; i < N; i += stride) {
        f32x2 xrv[4];
        {
            float4 r0 = *(const float4*)&xr[(size_t)i * 64 + c0];
            float4 r1 = *(const float4*)&xr[(size_t)i * 64 + c0 + 4];
            xrv[0] = (f32x2){r0.x, r0.y}; xrv[1] = (f32x2){r0.z, r0.w};
            xrv[2] = (f32x2){r1.x, r1.y}; xrv[3] = (f32x2){r1.z, r1.w};
        }
        const int st = rowptr[i], en = rowptr[i + 1];
        float den = 0.f;
        f32x2 acc[4];
#pragma unroll
        for (int k = 0; k < 4; ++k) acc[k] = (f32x2){0.f, 0.f};

        if (st < en) {
            uint4 w0 = *(const uint4*)(xlh + ((size_t)colsrc[st + g] << 6) + c0);
            uint4 w1 = *(const uint4*)(xlh + ((size_t)colsrc[st + 8 + g] << 6) + c0);
            int i0 = colsrc[st + 16 + g];
            int i1 = colsrc[st + 24 + g];
            for (int j = st; j < en; j += 16) {
                uint4 n0 = *(const uint4*)(xlh + ((size_t)i0 << 6) + c0);
                uint4 n1 = *(const uint4*)(xlh + ((size_t)i1 << 6) + c0);
                i0 = colsrc[j + 32 + g];
                i1 = colsrc[j + 40 + g];

#pragma unroll
                for (int q = 0; q < 2; ++q) {
                    const uint4 w = q ? w1 : w0;
                    f32x2 xv[4];
                    xv[0] = h2f2x(w.x); xv[1] = h2f2x(w.y);
                    xv[2] = h2f2x(w.z); xv[3] = h2f2x(w.w);
                    f32x2 sc = (f32x2){0.f, 0.f};
#pragma unroll
                    for (int k = 0; k < 4; ++k) {
                        f32x2 u = pk_add(xv[k], xrv[k]);
                        sc = pk_fma(u, a6[k], sc);
                        f32x2 ua = {__builtin_fabsf(u.x), __builtin_fabsf(u.y)};
                        sc = pk_fma(ua, a4[k], sc);
                    }
                    float p = reduce8_dpp(sc.x + sc.y);
                    p = (j + q * 8 + g < en) ? p : -INFINITY;
                    float pe = exp2f(p);
                    den += pe;
                    f32x2 pe2 = (f32x2){pe, pe};
#pragma unroll
                    for (int k = 0; k < 4; ++k) acc[k] = pk_fma(pe2, xv[k], acc[k]);
                }
                w0 = n0; w1 = n1;
            }
        }

        // merge the 8 edge groups
#pragma unroll
        for (int off = 8; off <= 32; off <<= 1) {
            den += __shfl_xor(den, off, 64);
#pragma unroll
            for (int k = 0; k < 4; ++k) {
                acc[k].x += __shfl_xor(acc[k].x, off, 64);
                acc[k].y += __shfl_xor(acc[k].y, off, 64);
            }
        }

        if (g == 0) {
            float4 b0 = *(const float4*)&bias[c0];
            float4 b1 = *(const float4*)&bias[c0 + 4];
            float bv[8] = {b0.x, b0.y, b0.z, b0.w, b1.x, b1.y, b1.z, b1.w};
            float inv = 1.f / (den + 1e-16f);
            float o[8];
#pragma unroll
            for (int k = 0; k < 8; ++k) {
                float av = (k & 1) ? acc[k >> 1].y : acc[k >> 1].x;
                o[k] = fmaf(av, inv, bv[k]);
            }
            *(float4*)&out[(size_t)i * 64 + c0] = make_float4(o[0], o[1], o[2], o[3]);
            *(float4*)&out[(size_t)i * 64 + c0 + 4] = make_float4(o[4], o[5], o[6], o[7]);
        }
    }
}

// ---------------- launch ----------------

static inline size_t align_up(size_t v, size_t a) { return (v + a - 1) & ~(a - 1); }

extern "C" void kernel_launch(void* const* d_in, const int* in_sizes, int n_in,
                              void* d_out, int out_size, void* d_ws, size_t ws_size,
                              hipStream_t stream) {
    const float* x = (const float*)d_in[0];
    const int* ei = (const int*)d_in[1];
    const int N = in_sizes[0] / FIN;
    const int E = in_sizes[1] / 2;
    const int* esrc = ei;
    const int* edst = ei + E;

    const float* Wl1 = (const float*)d_in[2];
    const float* Wr1 = (const float*)d_in[3];
    const float* att1 = (const float*)d_in[4];
    const float* b1 = (const float*)d_in[5];
    const float* Wl2 = (const float*)d_in[6];
    const float* Wr2 = (const float*)d_in[7];
    const float* att2 = (const float*)d_in[8];
    const float* b2 = (const float*)d_in[9];
    const float* Wl3 = (const float*)d_in[10];
    const float* Wr3 = (const float*)d_in[11];
    const float* att3 = (const float*)d_in[12];
    const float* b3 = (const float*)d_in[13];
    const float* Wl4 = (const float*)d_in[14];
    const float* Wr4 = (const float*)d_in[15];
    const float* att4 = (const float*)d_in[16];
    const float* b4 = (const float*)d_in[17];

    const int nb = (N + 1023) / 1024;
    const int span = (N + 7) / 8;

    size_t off = 0;
    char* w = (char*)d_ws;
    auto alloc = [&](size_t bytes) {
        char* p = w + off;
        off = align_up(off + bytes, 256);
        return p;
    };
    int* rowptr = (int*)alloc((size_t)(N + 1) * 4);
    int* nfill = (int*)alloc((size_t)N * 4);
    int* incl = (int*)alloc((size_t)N * 4);
    int* partial = (int*)alloc(1024 * 4);
    int* colids = (int*)alloc((size_t)E * 4);
    int* colsrc = (int*)alloc((size_t)(E + 64) * 4);   // +64 zero pad: unclamped prefetch
    __half* xb16 = (__half*)alloc((size_t)N * FIN * 2);
    __half* xlh = (__half*)alloc((size_t)N * FIN * 2);
    float* xr = (float*)alloc((size_t)N * FIN * 4);
    __half* Wz1 = (__half*)alloc(65536);
    __half* Wz2 = (__half*)alloc(65536);
    __half* Wz3 = (__half*)alloc(65536);
    __half* Wz4 = (__half*)alloc(32768);
    if (off > ws_size) return;

    // CSR build (deterministic: per-node lists sorted by edge id)
    hipMemsetAsync(nfill, 0, (size_t)N * 4, stream);
    hipMemsetAsync(colsrc + E, 0, 64 * 4, stream);
    k_hist_part<<<2048, 256, 0, stream>>>(edst, nfill, E, span);
    k_scan1<<<nb, 1024, 0, stream>>>(nfill, incl, partial, N);
    k_scan3<<<nb, 1024, 0, stream>>>(nfill, incl, partial, rowptr, nfill, N, nb);
    k_scatter_part<<<2048, 256, 0, stream>>>(edst, rowptr, nfill, colids, E, span);
    k_sort<<<(N + 3) / 4, 256, 0, stream>>>(rowptr, colids, esrc, colsrc, N);

    // weight prep (all layers, one launch)
    WprepArgs wa;
    wa.Wl[0] = Wl1; wa.Wl[1] = Wl2; wa.Wl[2] = Wl3; wa.Wl[3] = Wl4;
    wa.Wr[0] = Wr1; wa.Wr[1] = Wr2; wa.Wr[2] = Wr3; wa.Wr[3] = Wr4;
    wa.Wz[0] = Wz1; wa.Wz[1] = Wz2; wa.Wz[2] = Wz3; wa.Wz[3] = Wz4;
    k_wprep_all<<<56, 256, 0, stream>>>(wa);

    const int gg = (N + 63) / 64;
    const int gf = (N + 3) / 4;   // 1 node per wave: fine-grained tail backfill

    k_gemm_mfma<128, true><<<gg, 256, 0, stream>>>(x, Wz1, xlh, xr, N);
    k_fused2<true><<<gf, 256, 0, stream>>>(xlh, xr, rowptr, colsrc, att1, b1, xb16, N);
    k_gemm_mfma<128, false><<<gg, 256, 0, stream>>>(xb16, Wz2, xlh, xr, N);
    k_fused2<true><<<gf, 256, 0, stream>>>(xlh, xr, rowptr, colsrc, att2, b2, xb16, N);
    k_gemm_mfma<128, false><<<gg, 256, 0, stream>>>(xb16, Wz3, xlh, xr, N);
    k_fused2<true><<<gf, 256, 0, stream>>>(xlh, xr, rowptr, colsrc, att3, b3, xb16, N);
    k_gemm_mfma<64, false><<<gg, 256, 0, stream>>>(xb16, Wz4, xlh, xr, N);
    k_fused1<<<gf, 256, 0, stream>>>(xlh, xr, rowptr, colsrc, att4, b4, (float*)d_out, N);
}

// Round 13
// 380.421 us; speedup vs baseline: 1.1270x; 1.0134x over previous
//
#include <hip/hip_runtime.h>
#include <hip/hip_fp16.h>
#include <math.h>
#include <limits.h>

#define FIN 128
#define NEG_SLOPE 0.2f

typedef _Float16 f16x8 __attribute__((ext_vector_type(8)));
typedef float f32x4 __attribute__((ext_vector_type(4)));
typedef float f32x2 __attribute__((ext_vector_type(2)));

// ---- VOP3P packed fp32 (CDNA dual-FP32). hipcc never auto-forms these. ----
static __device__ __forceinline__ f32x2 pk_add(f32x2 a, f32x2 b) {
    f32x2 d; asm("v_pk_add_f32 %0, %1, %2" : "=v"(d) : "v"(a), "v"(b)); return d;
}
static __device__ __forceinline__ f32x2 pk_fma(f32x2 a, f32x2 b, f32x2 c) {
    f32x2 d; asm("v_pk_fma_f32 %0, %1, %2, %3" : "=v"(d) : "v"(a), "v"(b), "v"(c)); return d;
}

static __device__ __forceinline__ f32x2 h2f2x(unsigned int u) {
    __half2 h = *reinterpret_cast<__half2*>(&u);
    float2 f = __half22float2(h);
    return (f32x2){f.x, f.y};
}

// DPP tree-add within 8-lane groups (xor1, xor2, xor4). Full-rate VALU, no LDS.
template <int CTRL>
static __device__ __forceinline__ float dpp_add(float x) {
    int t = __builtin_amdgcn_update_dpp(0, __builtin_bit_cast(int, x), CTRL, 0xF, 0xF, true);
    return x + __builtin_bit_cast(float, t);
}
static __device__ __forceinline__ float reduce8_dpp(float p) {
    p = dpp_add<0xB1>(p);    // quad_perm [1,0,3,2]  : xor 1
    p = dpp_add<0x4E>(p);    // quad_perm [2,3,0,1]  : xor 2
    p = dpp_add<0x141>(p);   // row_half_mirror      : xor 4
    return p;
}

// ---------------- CSR build (XCD-range-partitioned hist/scatter) ----------------

__global__ void k_hist_part(const int* __restrict__ dst, int* __restrict__ counts,
                            int E, int span) {
    const int r = blockIdx.x & 7;
    const int chunk = blockIdx.x >> 3;
    const int nchunks = gridDim.x >> 3;
    const int lo = r * span, hi = lo + span;
    const int per = (E + nchunks - 1) / nchunks;
    const int e1 = min(E, (chunk + 1) * per);
    for (int e = chunk * per + threadIdx.x; e < e1; e += blockDim.x) {
        int d = dst[e];
        if (d >= lo && d < hi) atomicAdd(&counts[d], 1);
    }
}

__global__ void k_scatter_part(const int* __restrict__ dst, const int* __restrict__ rowptr,
                               int* __restrict__ nfill, int* __restrict__ colids,
                               int E, int span) {
    const int r = blockIdx.x & 7;
    const int chunk = blockIdx.x >> 3;
    const int nchunks = gridDim.x >> 3;
    const int lo = r * span, hi = lo + span;
    const int per = (E + nchunks - 1) / nchunks;
    const int e1 = min(E, (chunk + 1) * per);
    for (int e = chunk * per + threadIdx.x; e < e1; e += blockDim.x) {
        int d = dst[e];
        if (d >= lo && d < hi) {
            int pos = atomicAdd(&nfill[d], 1);
            colids[rowptr[d] + pos] = e;
        }
    }
}

__global__ void k_scan1(const int* __restrict__ counts, int* __restrict__ incl,
                        int* __restrict__ partial, int n) {
    __shared__ int tmp[1024];
    int tid = threadIdx.x, base = blockIdx.x * 1024;
    int v = (base + tid < n) ? counts[base + tid] : 0;
    tmp[tid] = v;
    __syncthreads();
    for (int off = 1; off < 1024; off <<= 1) {
        int t = (tid >= off) ? tmp[tid - off] : 0;
        __syncthreads();
        tmp[tid] += t;
        __syncthreads();
    }
    if (base + tid < n) incl[base + tid] = tmp[tid];
    if (tid == 1023) partial[blockIdx.x] = tmp[1023];
}

__global__ void k_scan3(const int* __restrict__ counts, const int* __restrict__ incl,
                        const int* __restrict__ partial, int* __restrict__ rowptr,
                        int* __restrict__ nfill, int n, int nb) {
    __shared__ int sbase;
    if (threadIdx.x == 0) {
        int b = 0;
        for (int p = 0; p < (int)blockIdx.x; ++p) b += partial[p];
        sbase = b;
        if ((int)blockIdx.x == nb - 1) {
            int tot = b;
            for (int p = blockIdx.x; p < nb; ++p) tot += partial[p];
            rowptr[n] = tot;
        }
    }
    __syncthreads();
    int i = blockIdx.x * 1024 + threadIdx.x;
    if (i < n) {
        rowptr[i] = sbase + incl[i] - counts[i];
        nfill[i] = 0;
    }
}

__global__ void k_sort(const int* __restrict__ rowptr, const int* __restrict__ colids,
                       const int* __restrict__ esrc, int* __restrict__ colsrc, int n) {
    int node = blockIdx.x * 4 + (threadIdx.x >> 6);
    int lane = threadIdx.x & 63;
    if (node >= n) return;
    int s = rowptr[node], e = rowptr[node + 1];
    int d = e - s;
    if (d <= 0) return;
    if (d <= 64) {
        int v = (lane < d) ? colids[s + lane] : INT_MAX;
        int rank = 0;
        for (int j = 0; j < d; ++j) {
            int vj = __shfl(v, j, 64);
            rank += (vj < v) ? 1 : 0;
        }
        if (lane < d) colsrc[s + rank] = esrc[v];
    } else {
        if (lane == 0) {
            int last = -1;
            for (int k = 0; k < d; ++k) {
                int best = INT_MAX;
                for (int j = s; j < e; ++j) {
                    int id = colids[j];
                    if (id > last && id < best) best = id;
                }
                colsrc[s + k] = esrc[best];
                last = best;
            }
        }
    }
}

// ---- W prep (all 4 layers, one launch): fp32 Wl|Wr -> fp16 fragment-ordered ----

struct WprepArgs {
    const float* Wl[4];
    const float* Wr[4];
    __half* Wz[4];
};

__global__ void k_wprep_all(WprepArgs a) {
    int b = blockIdx.x;
    int layer = (b < 16) ? 0 : (b < 32) ? 1 : (b < 48) ? 2 : 3;
    int base = layer * 16;
    int HC = (layer == 3) ? 64 : 128;
    int NT = 2 * HC / 16;
    int tid = (b - base) * 256 + threadIdx.x;
    int l = tid & 63, c = tid >> 6;
    int ks = c / NT, nt = c % NT;
    int col = nt * 16 + (l & 15);
    int kbase = ks * 32 + ((l >> 4) << 3);
    const float* W = (col < HC) ? (a.Wl[layer] + col) : (a.Wr[layer] + (col - HC));
    __half h[8];
#pragma unroll
    for (int j = 0; j < 8; ++j) h[j] = __float2half(W[(size_t)(kbase + j) * HC]);
    *(uint4*)&a.Wz[layer][(size_t)tid * 8] = *(const uint4*)h;
}

// ---- MFMA GEMM: [n x 128] @ [128 x 2*HC](fp16) -> xl fp16 | xr fp32 ----

template <int HC, bool CVT>
__global__ void __launch_bounds__(256) k_gemm_mfma(
        const void* __restrict__ Ain, const __half* __restrict__ Wz,
        __half* __restrict__ xl, float* __restrict__ xr, int n) {
    constexpr int NT = 2 * HC / 16;
    const int l = threadIdx.x & 63;
    const int wid = threadIdx.x >> 6;
    const int r0 = (blockIdx.x * 4 + wid) * 16;
    if (r0 >= n) return;
    const int m = l & 15, kb = l >> 4;
    const int ra = min(r0 + m, n - 1);
    const f16x8* Bz = (const f16x8*)Wz;

    f32x4 acc[NT];
#pragma unroll
    for (int nt = 0; nt < NT; ++nt) acc[nt] = (f32x4){0.f, 0.f, 0.f, 0.f};

#pragma unroll
    for (int ks = 0; ks < 4; ++ks) {
        f16x8 a;
        if (CVT) {
            const float* Af = (const float*)Ain + (size_t)ra * FIN + kb * 8 + ks * 32;
            float4 f0 = *(const float4*)Af;
            float4 f1 = *(const float4*)(Af + 4);
            a[0] = (_Float16)f0.x; a[1] = (_Float16)f0.y;
            a[2] = (_Float16)f0.z; a[3] = (_Float16)f0.w;
            a[4] = (_Float16)f1.x; a[5] = (_Float16)f1.y;
            a[6] = (_Float16)f1.z; a[7] = (_Float16)f1.w;
        } else {
            a = *(const f16x8*)((const _Float16*)Ain + (size_t)ra * FIN + kb * 8 + ks * 32);
        }
#pragma unroll
        for (int nt = 0; nt < NT; ++nt) {
            f16x8 b = Bz[(ks * NT + nt) * 64 + l];
            acc[nt] = __builtin_amdgcn_mfma_f32_16x16x32_f16(a, b, acc[nt], 0, 0, 0);
        }
    }

    const int rb = r0 + kb * 4;
#pragma unroll
    for (int nt = 0; nt < NT; ++nt) {
        int c = nt * 16 + m;
        if (nt < NT / 2) {
#pragma unroll
            for (int r = 0; r < 4; ++r) {
                int row = rb + r;
                if (row < n) xl[(size_t)row * HC + c] = __float2half(acc[nt][r]);
            }
        } else {
            int cd = c - HC;
#pragma unroll
            for (int r = 0; r < 4; ++r) {
                int row = rb + r;
                if (row < n) xr[(size_t)row * HC + cd] = acc[nt][r];
            }
        }
    }
}

// ------- fused attention H=2: 16 lanes/edge, 8 edges/round, persistent waves -------
// Cross-node software pipeline: next node's rowptr issued at loop top (hidden
// under current edge loop); next node's colsrc issued before merge/write.

template <bool RELU>
__global__ void __launch_bounds__(256) k_fused2(
        const __half* __restrict__ xlh, const float* __restrict__ xr,
        const int* __restrict__ rowptr, const int* __restrict__ colsrc,
        const float* __restrict__ attc, const float* __restrict__ bias,
        __half* __restrict__ out, int N) {
    const int lane = threadIdx.x & 63;
    const int g = lane >> 4;
    const int s = lane & 15;
    const int c0 = s * 8;
    int i = blockIdx.x * 4 + (threadIdx.x >> 6);
    const int stride = gridDim.x * 4;
    const float L2E = 1.4426950408889634f;

    f32x2 a6[4], a4[4];
    {
        float4 a0 = *(const float4*)&attc[c0];
        float4 a1 = *(const float4*)&attc[c0 + 4];
        float t[8] = {a0.x, a0.y, a0.z, a0.w, a1.x, a1.y, a1.z, a1.w};
#pragma unroll
        for (int k = 0; k < 4; ++k) {
            a6[k] = (f32x2){0.6f * L2E * t[2 * k], 0.6f * L2E * t[2 * k + 1]};
            a4[k] = (f32x2){0.4f * L2E * t[2 * k], 0.4f * L2E * t[2 * k + 1]};
        }
    }

    if (i >= N) return;
    int st = rowptr[i];
    int en = rowptr[i + 1];
    // prime first node's colsrc indices (6 independent loads)
    int c0i = colsrc[st + g];
    int c1i = colsrc[st + 4 + g];
    int c2i = colsrc[st + 8 + g];
    int c3i = colsrc[st + 12 + g];
    int p0 = colsrc[st + 16 + g];
    int p1 = colsrc[st + 20 + g];

    while (true) {
        const int inext = i + stride;
        int nst = 0, nen = 0;
        if (inext < N) {                  // issue next rowptr early; hidden by edge loop
            nst = rowptr[inext];
            nen = rowptr[inext + 1];
        }
        f32x2 xrv[4];
        {
            float4 r0 = *(const float4*)&xr[(size_t)i * 128 + c0];
            float4 r1 = *(const float4*)&xr[(size_t)i * 128 + c0 + 4];
            xrv[0] = (f32x2){r0.x, r0.y}; xrv[1] = (f32x2){r0.z, r0.w};
            xrv[2] = (f32x2){r1.x, r1.y}; xrv[3] = (f32x2){r1.z, r1.w};
        }
        // first 16 edges' gathers (colsrc idx already in registers)
        uint4 w0 = *(const uint4*)(xlh + ((size_t)c0i << 7) + c0);
        uint4 w1 = *(const uint4*)(xlh + ((size_t)c1i << 7) + c0);
        uint4 w2 = *(const uint4*)(xlh + ((size_t)c2i << 7) + c0);
        uint4 w3 = *(const uint4*)(xlh + ((size_t)c3i << 7) + c0);
        int i0 = p0, i1 = p1;

        float den = 0.f;
        f32x2 acc[4];
#pragma unroll
        for (int k = 0; k < 4; ++k) acc[k] = (f32x2){0.f, 0.f};

        for (int j = st; j < en; j += 8) {
            uint4 n0 = *(const uint4*)(xlh + ((size_t)i0 << 7) + c0);
            uint4 n1 = *(const uint4*)(xlh + ((size_t)i1 << 7) + c0);
            i0 = colsrc[j + 24 + g];
            i1 = colsrc[j + 28 + g];

#pragma unroll
            for (int q = 0; q < 2; ++q) {
                const uint4 w = q ? w1 : w0;
                f32x2 xv[4];
                xv[0] = h2f2x(w.x); xv[1] = h2f2x(w.y);
                xv[2] = h2f2x(w.z); xv[3] = h2f2x(w.w);
                f32x2 sc = (f32x2){0.f, 0.f};
#pragma unroll
                for (int k = 0; k < 4; ++k) {
                    f32x2 u = pk_add(xv[k], xrv[k]);
                    sc = pk_fma(u, a6[k], sc);
                    f32x2 ua = {__builtin_fabsf(u.x), __builtin_fabsf(u.y)};
                    sc = pk_fma(ua, a4[k], sc);
                }
                float p = reduce8_dpp(sc.x + sc.y);
                p = (j + q * 4 + g < en) ? p : -INFINITY;   // exp2(-inf)=0
                float pe = exp2f(p);
                den += pe;
                f32x2 pe2 = (f32x2){pe, pe};
#pragma unroll
                for (int k = 0; k < 4; ++k) acc[k] = pk_fma(pe2, xv[k], acc[k]);
            }
            w0 = w2; w1 = w3; w2 = n0; w3 = n1;
        }

        // prefetch next node's colsrc (nst arrived during edge loop); hides under merge
        if (inext < N) {
            c0i = colsrc[nst + g];
            c1i = colsrc[nst + 4 + g];
            c2i = colsrc[nst + 8 + g];
            c3i = colsrc[nst + 12 + g];
            p0 = colsrc[nst + 16 + g];
            p1 = colsrc[nst + 20 + g];
        }

        // merge the 4 edge groups
#pragma unroll
        for (int off = 16; off <= 32; off <<= 1) {
            den += __shfl_xor(den, off, 64);
#pragma unroll
            for (int k = 0; k < 4; ++k) {
                acc[k].x += __shfl_xor(acc[k].x, off, 64);
                acc[k].y += __shfl_xor(acc[k].y, off, 64);
            }
        }

        if (g == 0) {
            float4 b0 = *(const float4*)&bias[c0];
            float4 b1 = *(const float4*)&bias[c0 + 4];
            float bv[8] = {b0.x, b0.y, b0.z, b0.w, b1.x, b1.y, b1.z, b1.w};
            float inv = 1.f / (den + 1e-16f);
            __half hb[8];
#pragma unroll
            for (int k = 0; k < 8; ++k) {
                float av = (k & 1) ? acc[k >> 1].y : acc[k >> 1].x;
                float o = fmaf(av, inv, bv[k]);
                if (RELU) o = fmaxf(o, 0.f);
                hb[k] = __float2half(o);
            }
            *(uint4*)&out[(size_t)i * 128 + c0] = *(const uint4*)hb;
        }

        if (inext >= N) break;
        i = inext; st = nst; en = nen;
    }
}

// ------- fused attention H=1 (layer 4): 8 lanes/edge, 16 edges/round, pipelined -------

__global__ void __launch_bounds__(256) k_fused1(
        const __half* __restrict__ xlh, const float* __restrict__ xr,
        const int* __restrict__ rowptr, const int* __restrict__ colsrc,
        const float* __restrict__ attc, const float* __restrict__ bias,
        float* __restrict__ out, int N) {
    const int lane = threadIdx.x & 63;
    const int g = lane >> 3;
    const int s = lane & 7;
    const int c0 = s * 8;
    int i = blockIdx.x * 4 + (threadIdx.x >> 6);
    const int stride = gridDim.x * 4;
    const float L2E = 1.4426950408889634f;

    f32x2 a6[4], a4[4];
    {
        float4 a0 = *(const float4*)&attc[c0];
        float4 a1 = *(const float4*)&attc[c0 + 4];
        float t[8] = {a0.x, a0.y, a0.z, a0.w, a1.x, a1.y, a1.z, a1.w};
#pragma unroll
        for (int k = 0; k < 4; ++k) {
            a6[k] = (f32x2){0.6f * L2E * t[2 * k], 0.6f * L2E * t[2 * k + 1]};
            a4[k] = (f32x2){0.4f * L2E * t[2 * k], 0.4f * L2E * t[2 * k + 1]};
        }
    }

    if (i >= N) return;
    int st = rowptr[i];
    int en = rowptr[i + 1];
    int c0i = colsrc[st + g];
    int c1i = colsrc[st + 8 + g];
    int p0 = colsrc[st + 16 + g];
    int p1 = colsrc[st + 24 + g];

    while (true) {
        const int inext = i + stride;
        int nst = 0, nen = 0;
        if (inext < N) {
            nst = rowptr[inext];
            nen = rowptr[inext + 1];
        }
        f32x2 xrv[4];
        {
            float4 r0 = *(const float4*)&xr[(size_t)i * 64 + c0];
            float4 r1 = *(const float4*)&xr[(size_t)i * 64 + c0 + 4];
            xrv[0] = (f32x2){r0.x, r0.y}; xrv[1] = (f32x2){r0.z, r0.w};
            xrv[2] = (f32x2){r1.x, r1.y}; xrv[3] = (f32x2){r1.z, r1.w};
        }
        uint4 w0 = *(const uint4*)(xlh + ((size_t)c0i << 6) + c0);
        uint4 w1 = *(const uint4*)(xlh + ((size_t)c1i << 6) + c0);
        int i0 = p0, i1 = p1;

        float den = 0.f;
        f32x2 acc[4];
#pragma unroll
        for (int k = 0; k < 4; ++k) acc[k] = (f32x2){0.f, 0.f};

        for (int j = st; j < en; j += 16) {
            uint4 n0 = *(const uint4*)(xlh + ((size_t)i0 << 6) + c0);
            uint4 n1 = *(const uint4*)(xlh + ((size_t)i1 << 6) + c0);
            i0 = colsrc[j + 32 + g];
            i1 = colsrc[j + 40 + g];

#pragma unroll
            for (int q = 0; q < 2; ++q) {
                const uint4 w = q ? w1 : w0;
                f32x2 xv[4];
                xv[0] = h2f2x(w.x); xv[1] = h2f2x(w.y);
                xv[2] = h2f2x(w.z); xv[3] = h2f2x(w.w);
                f32x2 sc = (f32x2){0.f, 0.f};
#pragma unroll
                for (int k = 0; k < 4; ++k) {
                    f32x2 u = pk_add(xv[k], xrv[k]);
                    sc = pk_fma(u, a6[k], sc);
                    f32x2 ua = {__builtin_fabsf(u.x), __builtin_fabsf(u.y)};
                    sc = pk_fma(ua, a4[k], sc);
                }
                float p = reduce8_dpp(sc.x + sc.y);
                p = (j + q * 8 + g < en) ? p : -INFINITY;
                float pe = exp2f(p);
                den += pe;
                f32x2 pe2 = (f32x2){pe, pe};
#pragma unroll
                for (int k = 0; k < 4; ++k) acc[k] = pk_fma(pe2, xv[k], acc[k]);
            }
            w0 = n0; w1 = n1;
        }

        if (inext < N) {
            c0i = colsrc[nst + g];
            c1i = colsrc[nst + 8 + g];
            p0 = colsrc[nst + 16 + g];
            p1 = colsrc[nst + 24 + g];
        }

        // merge the 8 edge groups
#pragma unroll
        for (int off = 8; off <= 32; off <<= 1) {
            den += __shfl_xor(den, off, 64);
#pragma unroll
            for (int k = 0; k < 4; ++k) {
                acc[k].x += __shfl_xor(acc[k].x, off, 64);
                acc[k].y += __shfl_xor(acc[k].y, off, 64);
            }
        }

        if (g == 0) {
            float4 b0 = *(const float4*)&bias[c0];
            float4 b1 = *(const float4*)&bias[c0 + 4];
            float bv[8] = {b0.x, b0.y, b0.z, b0.w, b1.x, b1.y, b1.z, b1.w};
            float inv = 1.f / (den + 1e-16f);
            float o[8];
#pragma unroll
            for (int k = 0; k < 8; ++k) {
                float av = (k & 1) ? acc[k >> 1].y : acc[k >> 1].x;
                o[k] = fmaf(av, inv, bv[k]);
            }
            *(float4*)&out[(size_t)i * 64 + c0] = make_float4(o[0], o[1], o[2], o[3]);
            *(float4*)&out[(size_t)i * 64 + c0 + 4] = make_float4(o[4], o[5], o[6], o[7]);
        }

        if (inext >= N) break;
        i = inext; st = nst; en = nen;
    }
}

// ---------------- launch ----------------

static inline size_t align_up(size_t v, size_t a) { return (v + a - 1) & ~(a - 1); }

extern "C" void kernel_launch(void* const* d_in, const int* in_sizes, int n_in,
                              void* d_out, int out_size, void* d_ws, size_t ws_size,
                              hipStream_t stream) {
    const float* x = (const float*)d_in[0];
    const int* ei = (const int*)d_in[1];
    const int N = in_sizes[0] / FIN;
    const int E = in_sizes[1] / 2;
    const int* esrc = ei;
    const int* edst = ei + E;

    const float* Wl1 = (const float*)d_in[2];
    const float* Wr1 = (const float*)d_in[3];
    const float* att1 = (const float*)d_in[4];
    const float* b1 = (const float*)d_in[5];
    const float* Wl2 = (const float*)d_in[6];
    const float* Wr2 = (const float*)d_in[7];
    const float* att2 = (const float*)d_in[8];
    const float* b2 = (const float*)d_in[9];
    const float* Wl3 = (const float*)d_in[10];
    const float* Wr3 = (const float*)d_in[11];
    const float* att3 = (const float*)d_in[12];
    const float* b3 = (const float*)d_in[13];
    const float* Wl4 = (const float*)d_in[14];
    const float* Wr4 = (const float*)d_in[15];
    const float* att4 = (const float*)d_in[16];
    const float* b4 = (const float*)d_in[17];

    const int nb = (N + 1023) / 1024;
    const int span = (N + 7) / 8;

    size_t off = 0;
    char* w = (char*)d_ws;
    auto alloc = [&](size_t bytes) {
        char* p = w + off;
        off = align_up(off + bytes, 256);
        return p;
    };
    int* rowptr = (int*)alloc((size_t)(N + 1) * 4);
    int* nfill = (int*)alloc((size_t)N * 4);
    int* incl = (int*)alloc((size_t)N * 4);
    int* partial = (int*)alloc(1024 * 4);
    int* colids = (int*)alloc((size_t)E * 4);
    int* colsrc = (int*)alloc((size_t)(E + 64) * 4);   // +64 zero pad: unclamped prefetch
    __half* xb16 = (__half*)alloc((size_t)N * FIN * 2);
    __half* xlh = (__half*)alloc((size_t)N * FIN * 2);
    float* xr = (float*)alloc((size_t)N * FIN * 4);
    __half* Wz1 = (__half*)alloc(65536);
    __half* Wz2 = (__half*)alloc(65536);
    __half* Wz3 = (__half*)alloc(65536);
    __half* Wz4 = (__half*)alloc(32768);
    if (off > ws_size) return;

    // CSR build (deterministic: per-node lists sorted by edge id)
    hipMemsetAsync(nfill, 0, (size_t)N * 4, stream);
    hipMemsetAsync(colsrc + E, 0, 64 * 4, stream);
    k_hist_part<<<2048, 256, 0, stream>>>(edst, nfill, E, span);
    k_scan1<<<nb, 1024, 0, stream>>>(nfill, incl, partial, N);
    k_scan3<<<nb, 1024, 0, stream>>>(nfill, incl, partial, rowptr, nfill, N, nb);
    k_scatter_part<<<2048, 256, 0, stream>>>(edst, rowptr, nfill, colids, E, span);
    k_sort<<<(N + 3) / 4, 256, 0, stream>>>(rowptr, colids, esrc, colsrc, N);

    // weight prep (all layers, one launch)
    WprepArgs wa;
    wa.Wl[0] = Wl1; wa.Wl[1] = Wl2; wa.Wl[2] = Wl3; wa.Wl[3] = Wl4;
    wa.Wr[0] = Wr1; wa.Wr[1] = Wr2; wa.Wr[2] = Wr3; wa.Wr[3] = Wr4;
    wa.Wz[0] = Wz1; wa.Wz[1] = Wz2; wa.Wz[2] = Wz3; wa.Wz[3] = Wz4;
    k_wprep_all<<<56, 256, 0, stream>>>(wa);

    const int gg = (N + 63) / 64;
    const int gf = 2048;   // persistent waves: ~6 nodes/wave -> cross-node pipeline pays

    k_gemm_mfma<128, true><<<gg, 256, 0, stream>>>(x, Wz1, xlh, xr, N);
    k_fused2<true><<<gf, 256, 0, stream>>>(xlh, xr, rowptr, colsrc, att1, b1, xb16, N);
    k_gemm_mfma<128, false><<<gg, 256, 0, stream>>>(xb16, Wz2, xlh, xr, N);
    k_fused2<true><<<gf, 256, 0, stream>>>(xlh, xr, rowptr, colsrc, att2, b2, xb16, N);
    k_gemm_mfma<128, false><<<gg, 256, 0, stream>>>(xb16, Wz3, xlh, xr, N);
    k_fused2<true><<<gf, 256, 0, stream>>>(xlh, xr, rowptr, colsrc, att3, b3, xb16, N);
    k_gemm_mfma<64, false><<<gg, 256, 0, stream>>>(xb16, Wz4, xlh, xr, N);
    k_fused1<<<gf, 256, 0, stream>>>(xlh, xr, rowptr, colsrc, att4, b4, (float*)d_out, N);
}